// Round 2
// baseline (1075.299 us; speedup 1.0000x reference)
//
#include <hip/hip_runtime.h>
#include <cstdint>

#define S_LEN 2048
#define DMODEL 2560
#define NHEADS 32
#define HDIM 80
#define DINTER 10240

typedef unsigned short u16;
typedef __bf16 bf16x8 __attribute__((ext_vector_type(8)));
typedef float f32x4 __attribute__((ext_vector_type(4)));

__device__ __forceinline__ float us2f(u16 u) {
  return __builtin_bit_cast(float, ((uint32_t)u) << 16);
}
__device__ __forceinline__ u16 f2us(float f) {
  uint32_t x = __builtin_bit_cast(uint32_t, f);
  x += 0x7fffu + ((x >> 16) & 1u);
  return (u16)(x >> 16);
}

typedef __attribute__((address_space(1))) void gas_void;
typedef __attribute__((address_space(3))) void las_void;
__device__ __forceinline__ void gld16(const void* g, void* l) {
  // async global->LDS, 16B/lane; LDS dest = wave-uniform base + lane*16
  __builtin_amdgcn_global_load_lds((gas_void*)g, (las_void*)l, 16, 0, 0);
}

// ---------------------------------------------------------------------------
// fp32 -> bf16 conversion, 8 elements/thread
// ---------------------------------------------------------------------------
__global__ void f2b_kernel(const float* __restrict__ src, u16* __restrict__ dst) {
  const size_t i = ((size_t)blockIdx.x * 256 + threadIdx.x) * 8;
  const float4 a = *(const float4*)(src + i);
  const float4 b = *(const float4*)(src + i + 4);
  u16 o[8] = {f2us(a.x), f2us(a.y), f2us(a.z), f2us(a.w),
              f2us(b.x), f2us(b.y), f2us(b.z), f2us(b.w)};
  *(uint4*)(dst + i) = *(uint4*)o;
}

// ---------------------------------------------------------------------------
// LayerNorm: fp32 in, bf16 out. One block per row (2560 = 256 x 10)
// ---------------------------------------------------------------------------
__global__ void ln_kernel(const float* __restrict__ x, const float* __restrict__ w,
                          const float* __restrict__ b, u16* __restrict__ h) {
  const int s = blockIdx.x, tid = threadIdx.x;
  const float* xr = x + (size_t)s * DMODEL;
  float v[10];
  float sum = 0.f, sq = 0.f;
#pragma unroll
  for (int j = 0; j < 10; j++) {
    v[j] = xr[tid + j * 256];
    sum += v[j];
    sq += v[j] * v[j];
  }
#pragma unroll
  for (int o = 32; o > 0; o >>= 1) {
    sum += __shfl_down(sum, o, 64);
    sq += __shfl_down(sq, o, 64);
  }
  __shared__ float red[8];
  const int wave = tid >> 6, lane = tid & 63;
  if (lane == 0) { red[wave] = sum; red[4 + wave] = sq; }
  __syncthreads();
  sum = red[0] + red[1] + red[2] + red[3];
  sq = red[4] + red[5] + red[6] + red[7];
  const float mu = sum * (1.0f / DMODEL);
  const float var = sq * (1.0f / DMODEL) - mu * mu;
  const float rstd = rsqrtf(var + 1e-5f);
  u16* hr = h + (size_t)s * DMODEL;
#pragma unroll
  for (int j = 0; j < 10; j++) {
    const int d = tid + j * 256;
    hr[d] = f2us((v[j] - mu) * rstd * w[d] + b[d]);
  }
}

// ---------------------------------------------------------------------------
// GEMM: C[M][N] = act(A[M][K] * B[N][K]^T + bias[N]); bf16 in, fp32 acc.
// 128x128 tile, BK=32, 256 threads (4 waves, 2x2 wave grid, 4x4 MFMA tiles).
// ACT: 0 = none, 1 = tanh-approx GELU.  OUTF32: 1 = fp32 out, 0 = bf16 out.
// ---------------------------------------------------------------------------
template <int ACT, int OUTF32>
__global__ void gemm_bt(const u16* __restrict__ A, const u16* __restrict__ B,
                        const float* __restrict__ bias, void* __restrict__ Cv,
                        int M, int N, int K) {
  __shared__ __align__(16) u16 As[128 * 32];
  __shared__ __align__(16) u16 Bs[128 * 32];
  const int tid = threadIdx.x;
  const int wave = tid >> 6, lane = tid & 63;
  const int quad = lane >> 4, l15 = lane & 15;
  const int wm = wave >> 1, wn = wave & 1;
  const int bm = blockIdx.y, bn = blockIdx.x;

  // staging coords: 16B per lane, 4 lanes per 32-elem row, 16 rows per wave-instr
  const int srow = lane >> 2;
  const int scol = (lane & 3) * 8;
  const size_t aBase = (size_t)(bm * 128 + wave * 32 + srow) * K + scol;
  const size_t aBase2 = aBase + (size_t)16 * K;
  const size_t bBase = (size_t)(bn * 128 + wave * 32 + srow) * K + scol;
  const size_t bBase2 = bBase + (size_t)16 * K;
  u16* AsW0 = As + (wave * 32) * 32;
  u16* AsW1 = As + (wave * 32 + 16) * 32;
  u16* BsW0 = Bs + (wave * 32) * 32;
  u16* BsW1 = Bs + (wave * 32 + 16) * 32;

  f32x4 acc[4][4] = {};

  for (int k0 = 0; k0 < K; k0 += 32) {
    gld16(A + aBase + k0, AsW0);
    gld16(A + aBase2 + k0, AsW1);
    gld16(B + bBase + k0, BsW0);
    gld16(B + bBase2 + k0, BsW1);
    __syncthreads();
    bf16x8 af[4], bf[4];
#pragma unroll
    for (int mt = 0; mt < 4; mt++)
      af[mt] = *(const bf16x8*)&As[(wm * 64 + mt * 16 + l15) * 32 + quad * 8];
#pragma unroll
    for (int nt = 0; nt < 4; nt++)
      bf[nt] = *(const bf16x8*)&Bs[(wn * 64 + nt * 16 + l15) * 32 + quad * 8];
#pragma unroll
    for (int mt = 0; mt < 4; mt++)
#pragma unroll
      for (int nt = 0; nt < 4; nt++)
        acc[mt][nt] =
            __builtin_amdgcn_mfma_f32_16x16x32_bf16(af[mt], bf[nt], acc[mt][nt], 0, 0, 0);
    __syncthreads();
  }

#pragma unroll
  for (int nt = 0; nt < 4; nt++) {
    const int col = bn * 128 + wn * 64 + nt * 16 + l15;
    const float bv = bias[col];
#pragma unroll
    for (int mt = 0; mt < 4; mt++) {
      const int row0 = bm * 128 + wm * 64 + mt * 16 + quad * 4;
#pragma unroll
      for (int r = 0; r < 4; r++) {
        float v = acc[mt][nt][r] + bv;
        if (ACT == 1) {
          const float t = v * (0.7978845608f + 0.0356774081f * v * v);
          v = 0.5f * v * (1.0f + tanhf(t));
        }
        if (OUTF32)
          ((float*)Cv)[(size_t)(row0 + r) * N + col] = v;
        else
          ((u16*)Cv)[(size_t)(row0 + r) * N + col] = f2us(v);
      }
    }
  }
}

// ---------------------------------------------------------------------------
// RoPE in-place on bf16 qkv (q and k sections, first 32 dims of each head).
// ---------------------------------------------------------------------------
__global__ void rope_kernel(u16* __restrict__ qkv, const int* __restrict__ pos) {
  const int idx = blockIdx.x * 256 + threadIdx.x;  // 2048*32*2*16 total
  const int i = idx & 15;
  const int which = (idx >> 4) & 1;
  const int hh = (idx >> 5) & 31;
  const int s = idx >> 10;
  const float p = (float)pos[s];
  const float freq = p * expf(-0.57564627324851f * (float)i);  // ln(1e4)/16
  float sn, c;
  sincosf(freq, &sn, &c);
  u16* base = qkv + (size_t)s * (3 * DMODEL) + which * DMODEL + hh * HDIM + i;
  const float t0 = us2f(base[0]), t1 = us2f(base[16]);
  base[0] = f2us(t0 * c - t1 * sn);
  base[16] = f2us(t1 * c + t0 * sn);
}

// ---------------------------------------------------------------------------
// Flash attention (causal), bf16 in/out. Grid: (S/64, H). 4 waves; each wave
// owns 16 q-rows. KT=32 key columns per iteration; hd 80 padded to 96.
// ---------------------------------------------------------------------------
__global__ void attn_kernel(const u16* __restrict__ qkv, u16* __restrict__ y) {
  const int qt = (int)gridDim.x - 1 - (int)blockIdx.x;  // longest blocks first
  const int h = blockIdx.y;
  const int tid = threadIdx.x, wave = tid >> 6, lane = tid & 63;
  const int quad = lane >> 4, l15 = lane & 15;
  const int qbase = qt * 64;

  __shared__ __align__(16) u16 Qs[64 * 96];
  __shared__ __align__(16) u16 Ks[32 * 96];
  __shared__ __align__(16) u16 Vts[80 * 40];  // transposed V, stride 40
  __shared__ __align__(16) u16 Ps[4][16 * 40];

  for (int i = tid; i < 64 * 96; i += 256) Qs[i] = 0;
  for (int i = tid; i < 32 * 96; i += 256) Ks[i] = 0;
  __syncthreads();

  {  // stage Q once, folding in 1/sqrt(80)
    const int r = tid >> 2, c = tid & 3;
    const u16* src = qkv + (size_t)(qbase + r) * (3 * DMODEL) + h * HDIM + c * 20;
    u16* dst = Qs + r * 96 + c * 20;
#pragma unroll
    for (int j = 0; j < 5; j++) {
      ushort4 uv = *(const ushort4*)(src + j * 4);
      ushort4 ov;
      ov.x = f2us(us2f(uv.x) * 0.11180339887f);
      ov.y = f2us(us2f(uv.y) * 0.11180339887f);
      ov.z = f2us(us2f(uv.z) * 0.11180339887f);
      ov.w = f2us(us2f(uv.w) * 0.11180339887f);
      *(ushort4*)(dst + j * 4) = ov;
    }
  }

  float m_i[4], l_i[4];
  f32x4 oacc[5] = {};
#pragma unroll
  for (int r = 0; r < 4; r++) { m_i[r] = -1e30f; l_i[r] = 0.f; }

  const int n_iter = qt * 2 + 2;
  __syncthreads();

  for (int it = 0; it < n_iter; ++it) {
    const int kc0 = it * 32;
    if (tid < 128) {  // waves 0-1: stage K rows
      const int r = tid >> 2, c = tid & 3;
      const u16* src =
          qkv + (size_t)(kc0 + r) * (3 * DMODEL) + DMODEL + h * HDIM + c * 20;
      u16* dst = Ks + r * 96 + c * 20;
#pragma unroll
      for (int j = 0; j < 5; j++)
        *(ushort4*)(dst + j * 4) = *(const ushort4*)(src + j * 4);
    } else {  // waves 2-3: stage V transposed
      const int u = tid - 128;
      const int r = u >> 2, c = u & 3;
      const u16* src =
          qkv + (size_t)(kc0 + r) * (3 * DMODEL) + 2 * DMODEL + h * HDIM + c * 20;
#pragma unroll
      for (int j = 0; j < 5; j++) {
        ushort4 vv = *(const ushort4*)(src + j * 4);
        const int d0 = c * 20 + j * 4;
        Vts[(d0 + 0) * 40 + r] = vv.x;
        Vts[(d0 + 1) * 40 + r] = vv.y;
        Vts[(d0 + 2) * 40 + r] = vv.z;
        Vts[(d0 + 3) * 40 + r] = vv.w;
      }
    }
    __syncthreads();

    // S = Q K^T (16 rows x 32 cols per wave), 3 K-steps over padded hd=96
    f32x4 st[2] = {};
#pragma unroll
    for (int ks = 0; ks < 3; ks++) {
      bf16x8 aq = *(const bf16x8*)&Qs[(wave * 16 + l15) * 96 + ks * 32 + quad * 8];
#pragma unroll
      for (int t = 0; t < 2; t++) {
        bf16x8 bk = *(const bf16x8*)&Ks[(t * 16 + l15) * 96 + ks * 32 + quad * 8];
        st[t] = __builtin_amdgcn_mfma_f32_16x16x32_bf16(aq, bk, st[t], 0, 0, 0);
      }
    }

    // causal mask + online softmax (rows = quad*4+r, cols = t*16+l15)
    float sv[2][4], mx[4];
#pragma unroll
    for (int r = 0; r < 4; r++) {
      const int qr = qbase + wave * 16 + quad * 4 + r;
#pragma unroll
      for (int t = 0; t < 2; t++) {
        const int kc = kc0 + t * 16 + l15;
        sv[t][r] = (kc <= qr) ? st[t][r] : -1e30f;
      }
      mx[r] = fmaxf(sv[0][r], sv[1][r]);
    }
#pragma unroll
    for (int o = 1; o < 16; o <<= 1)
#pragma unroll
      for (int r = 0; r < 4; r++) mx[r] = fmaxf(mx[r], __shfl_xor(mx[r], o, 64));

    float alpha[4], rs[4];
#pragma unroll
    for (int r = 0; r < 4; r++) {
      const float mnew = fmaxf(m_i[r], mx[r]);
      alpha[r] = __expf(m_i[r] - mnew);
      m_i[r] = mnew;
      const float p0 = __expf(sv[0][r] - mnew);
      const float p1 = __expf(sv[1][r] - mnew);
      rs[r] = p0 + p1;
      Ps[wave][(quad * 4 + r) * 40 + l15] = f2us(p0);
      Ps[wave][(quad * 4 + r) * 40 + 16 + l15] = f2us(p1);
    }
#pragma unroll
    for (int o = 1; o < 16; o <<= 1)
#pragma unroll
      for (int r = 0; r < 4; r++) rs[r] += __shfl_xor(rs[r], o, 64);
#pragma unroll
    for (int r = 0; r < 4; r++) l_i[r] = l_i[r] * alpha[r] + rs[r];
#pragma unroll
    for (int dt = 0; dt < 5; dt++)
#pragma unroll
      for (int r = 0; r < 4; r++) oacc[dt][r] *= alpha[r];

    // O += P V  (P via LDS round-trip into A-layout; V from transposed LDS)
    bf16x8 pf = *(const bf16x8*)&Ps[wave][l15 * 40 + quad * 8];
#pragma unroll
    for (int dt = 0; dt < 5; dt++) {
      bf16x8 vf = *(const bf16x8*)&Vts[(dt * 16 + l15) * 40 + quad * 8];
      oacc[dt] = __builtin_amdgcn_mfma_f32_16x16x32_bf16(pf, vf, oacc[dt], 0, 0, 0);
    }
    __syncthreads();
  }

#pragma unroll
  for (int dt = 0; dt < 5; dt++)
#pragma unroll
    for (int r = 0; r < 4; r++) {
      const int row = qbase + wave * 16 + quad * 4 + r;
      y[(size_t)row * DMODEL + h * HDIM + dt * 16 + l15] = f2us(oacc[dt][r] / l_i[r]);
    }
}

// ---------------------------------------------------------------------------
// out = x + attn_out + ffn_out  (all fp32), 4 elements/thread
// ---------------------------------------------------------------------------
__global__ void add3_kernel(const float* __restrict__ x, const float* __restrict__ a,
                            const float* __restrict__ f, float* __restrict__ out) {
  const size_t idx = ((size_t)blockIdx.x * 256 + threadIdx.x) * 4;
  const float4 vx = *(const float4*)(x + idx);
  const float4 va = *(const float4*)(a + idx);
  const float4 vf = *(const float4*)(f + idx);
  float4 vo;
  vo.x = vx.x + va.x + vf.x;
  vo.y = vx.y + va.y + vf.y;
  vo.z = vx.z + va.z + vf.z;
  vo.w = vx.w + va.w + vf.w;
  *(float4*)(out + idx) = vo;
}

extern "C" void kernel_launch(void* const* d_in, const int* in_sizes, int n_in,
                              void* d_out, int out_size, void* d_ws, size_t ws_size,
                              hipStream_t stream) {
  const float* x = (const float*)d_in[0];
  const int* pos = (const int*)d_in[1];
  // d_in[2] = mask (tril) -- causal structure applied analytically
  const float* ln_w = (const float*)d_in[3];
  const float* ln_b = (const float*)d_in[4];
  const float* wqkv_w = (const float*)d_in[5];
  const float* wqkv_b = (const float*)d_in[6];
  const float* wo_w = (const float*)d_in[7];
  const float* wo_b = (const float*)d_in[8];
  const float* w1_w = (const float*)d_in[9];
  const float* w1_b = (const float*)d_in[10];
  const float* w2_w = (const float*)d_in[11];
  const float* w2_b = (const float*)d_in[12];
  float* out = (float*)d_out;

  char* ws = (char*)d_ws;
  // layout (bytes):
  //   A: [0,           52428800)  wbuf (bf16 weights, reused 4x)
  //      attn fp32 overlay at [16777216, 37748736) (after wo's 13107200)
  //   B: [52428800,    62914560)  h bf16
  //   C: [62914560,   104857600)  ffn1 bf16 (42MB); later qkv (31.5MB) + yAtt (10.5MB)
  //   D: [104857600,  125829120)  ffn2 fp32
  u16* wbuf = (u16*)(ws);
  float* attn = (float*)(ws + 16777216);
  u16* h = (u16*)(ws + 52428800);
  u16* ffn1 = (u16*)(ws + 62914560);
  u16* qkv = (u16*)(ws + 62914560);
  u16* yAtt = (u16*)(ws + 94371840);
  float* ffn2 = (float*)(ws + 104857600);

  // LN
  ln_kernel<<<S_LEN, 256, 0, stream>>>(x, ln_w, ln_b, h);

  // FFN branch first (so ffn1's region can be reused by qkv afterwards)
  f2b_kernel<<<(DINTER * DMODEL) / 2048, 256, 0, stream>>>(w1_w, wbuf);
  gemm_bt<1, 0><<<dim3(DINTER / 128, S_LEN / 128), 256, 0, stream>>>(
      h, wbuf, w1_b, ffn1, S_LEN, DINTER, DMODEL);
  f2b_kernel<<<(DMODEL * DINTER) / 2048, 256, 0, stream>>>(w2_w, wbuf);
  gemm_bt<0, 1><<<dim3(DMODEL / 128, S_LEN / 128), 256, 0, stream>>>(
      ffn1, wbuf, w2_b, ffn2, S_LEN, DMODEL, DINTER);

  // Attention branch
  f2b_kernel<<<(3 * DMODEL * DMODEL) / 2048, 256, 0, stream>>>(wqkv_w, wbuf);
  gemm_bt<0, 0><<<dim3(3 * DMODEL / 128, S_LEN / 128), 256, 0, stream>>>(
      h, wbuf, wqkv_b, qkv, S_LEN, 3 * DMODEL, DMODEL);
  rope_kernel<<<(S_LEN * NHEADS * 2 * 16) / 256, 256, 0, stream>>>(qkv, pos);
  attn_kernel<<<dim3(S_LEN / 64, NHEADS), 256, 0, stream>>>(qkv, yAtt);
  f2b_kernel<<<(DMODEL * DMODEL) / 2048, 256, 0, stream>>>(wo_w, wbuf);
  gemm_bt<0, 1><<<dim3(DMODEL / 128, S_LEN / 128), 256, 0, stream>>>(
      yAtt, wbuf, wo_b, attn, S_LEN, DMODEL, DMODEL);

  // Residual sum
  add3_kernel<<<(S_LEN * DMODEL / 4) / 256, 256, 0, stream>>>(x, attn, ffn2, out);
}

// Round 3
// 1030.507 us; speedup vs baseline: 1.0435x; 1.0435x over previous
//
#include <hip/hip_runtime.h>
#include <cstdint>

#define S_LEN 2048
#define DMODEL 2560
#define NHEADS 32
#define HDIM 80
#define DINTER 10240

typedef unsigned short u16;
typedef __bf16 bf16x8 __attribute__((ext_vector_type(8)));
typedef float f32x4 __attribute__((ext_vector_type(4)));

__device__ __forceinline__ float us2f(u16 u) {
  return __builtin_bit_cast(float, ((uint32_t)u) << 16);
}
__device__ __forceinline__ u16 f2us(float f) {
  uint32_t x = __builtin_bit_cast(uint32_t, f);
  x += 0x7fffu + ((x >> 16) & 1u);
  return (u16)(x >> 16);
}

typedef __attribute__((address_space(1))) void gas_void;
typedef __attribute__((address_space(3))) void las_void;
__device__ __forceinline__ void gld16(const void* g, void* l) {
  __builtin_amdgcn_global_load_lds((gas_void*)g, (las_void*)l, 16, 0, 0);
}

// ---------------------------------------------------------------------------
// fp32 -> bf16 conversion, 8 elements/thread
// ---------------------------------------------------------------------------
__global__ void f2b_kernel(const float* __restrict__ src, u16* __restrict__ dst) {
  const size_t i = ((size_t)blockIdx.x * 256 + threadIdx.x) * 8;
  const float4 a = *(const float4*)(src + i);
  const float4 b = *(const float4*)(src + i + 4);
  u16 o[8] = {f2us(a.x), f2us(a.y), f2us(a.z), f2us(a.w),
              f2us(b.x), f2us(b.y), f2us(b.z), f2us(b.w)};
  *(uint4*)(dst + i) = *(uint4*)o;
}

// ---------------------------------------------------------------------------
// out = x + wo_b[col] + w2_b[col]  (fp32), 4 elements/thread
// ---------------------------------------------------------------------------
__global__ void initout_kernel(const float* __restrict__ x,
                               const float* __restrict__ wo_b,
                               const float* __restrict__ w2_b,
                               float* __restrict__ out) {
  const size_t idx = ((size_t)blockIdx.x * 256 + threadIdx.x) * 4;
  const int c0 = (int)(idx % DMODEL);  // DMODEL % 4 == 0, no wrap
  const float4 vx = *(const float4*)(x + idx);
  const float4 b1 = *(const float4*)(wo_b + c0);
  const float4 b2 = *(const float4*)(w2_b + c0);
  float4 vo;
  vo.x = vx.x + b1.x + b2.x;
  vo.y = vx.y + b1.y + b2.y;
  vo.z = vx.z + b1.z + b2.z;
  vo.w = vx.w + b1.w + b2.w;
  *(float4*)(out + idx) = vo;
}

// ---------------------------------------------------------------------------
// LayerNorm: fp32 in, bf16 out. One block per row (2560 = 256 x 10)
// ---------------------------------------------------------------------------
__global__ void ln_kernel(const float* __restrict__ x, const float* __restrict__ w,
                          const float* __restrict__ b, u16* __restrict__ h) {
  const int s = blockIdx.x, tid = threadIdx.x;
  const float* xr = x + (size_t)s * DMODEL;
  float v[10];
  float sum = 0.f, sq = 0.f;
#pragma unroll
  for (int j = 0; j < 10; j++) {
    v[j] = xr[tid + j * 256];
    sum += v[j];
    sq += v[j] * v[j];
  }
#pragma unroll
  for (int o = 32; o > 0; o >>= 1) {
    sum += __shfl_down(sum, o, 64);
    sq += __shfl_down(sq, o, 64);
  }
  __shared__ float red[8];
  const int wave = tid >> 6, lane = tid & 63;
  if (lane == 0) { red[wave] = sum; red[4 + wave] = sq; }
  __syncthreads();
  sum = red[0] + red[1] + red[2] + red[3];
  sq = red[4] + red[5] + red[6] + red[7];
  const float mu = sum * (1.0f / DMODEL);
  const float var = sq * (1.0f / DMODEL) - mu * mu;
  const float rstd = rsqrtf(var + 1e-5f);
  u16* hr = h + (size_t)s * DMODEL;
#pragma unroll
  for (int j = 0; j < 10; j++) {
    const int d = tid + j * 256;
    hr[d] = f2us((v[j] - mu) * rstd * w[d] + b[d]);
  }
}

// ---------------------------------------------------------------------------
// GEMM: C[M][N] = act(A[M][K] * B[N][K]^T [+ bias[N]]); bf16 in, fp32 acc.
// 128x128 tile, BK=32, 256 threads (4 waves, 2x2 wave grid, 4x4 MFMA tiles).
// grid.z = K-split factor (chunk = K / gridDim.z).
// ACT: 0 none, 1 gelu-tanh. MODE: 0 bf16 store (+bias), 2 fp32 atomicAdd.
// Block swizzle: bands of 4 N-cols x 16 M-rows contiguous in dispatch order
// so each XCD's L2 keeps one B-strip hot (NB % 4 == 0, NM == 16 required).
// ---------------------------------------------------------------------------
template <int ACT, int MODE>
__global__ void gemm_bt(const u16* __restrict__ A, const u16* __restrict__ B,
                        const float* __restrict__ bias, void* __restrict__ Cv,
                        int M, int N, int K) {
  __shared__ __align__(16) u16 As[128 * 32];
  __shared__ __align__(16) u16 Bs[128 * 32];
  const int tid = threadIdx.x;
  const int wave = tid >> 6, lane = tid & 63;
  const int quad = lane >> 4, l15 = lane & 15;
  const int wm = wave >> 1, wn = wave & 1;

  const int flat = blockIdx.x + gridDim.x * blockIdx.y;
  const int r_ = flat & 63;
  const int bn = (flat >> 6) * 4 + (r_ & 3);
  const int bm = r_ >> 2;

  const int Kc = K / gridDim.z;
  const int kbeg = blockIdx.z * Kc;

  const int srow = lane >> 2;
  const int scol = (lane & 3) * 8;
  const size_t aBase = (size_t)(bm * 128 + wave * 32 + srow) * K + scol;
  const size_t aBase2 = aBase + (size_t)16 * K;
  const size_t bBase = (size_t)(bn * 128 + wave * 32 + srow) * K + scol;
  const size_t bBase2 = bBase + (size_t)16 * K;
  u16* AsW0 = As + (wave * 32) * 32;
  u16* AsW1 = As + (wave * 32 + 16) * 32;
  u16* BsW0 = Bs + (wave * 32) * 32;
  u16* BsW1 = Bs + (wave * 32 + 16) * 32;

  f32x4 acc[4][4] = {};

  for (int k0 = kbeg; k0 < kbeg + Kc; k0 += 32) {
    gld16(A + aBase + k0, AsW0);
    gld16(A + aBase2 + k0, AsW1);
    gld16(B + bBase + k0, BsW0);
    gld16(B + bBase2 + k0, BsW1);
    __syncthreads();
    bf16x8 af[4], bf[4];
#pragma unroll
    for (int mt = 0; mt < 4; mt++)
      af[mt] = *(const bf16x8*)&As[(wm * 64 + mt * 16 + l15) * 32 + quad * 8];
#pragma unroll
    for (int nt = 0; nt < 4; nt++)
      bf[nt] = *(const bf16x8*)&Bs[(wn * 64 + nt * 16 + l15) * 32 + quad * 8];
#pragma unroll
    for (int mt = 0; mt < 4; mt++)
#pragma unroll
      for (int nt = 0; nt < 4; nt++)
        acc[mt][nt] =
            __builtin_amdgcn_mfma_f32_16x16x32_bf16(af[mt], bf[nt], acc[mt][nt], 0, 0, 0);
    __syncthreads();
  }

#pragma unroll
  for (int nt = 0; nt < 4; nt++) {
    const int col = bn * 128 + wn * 64 + nt * 16 + l15;
    const float bv = (MODE == 0) ? bias[col] : 0.f;
#pragma unroll
    for (int mt = 0; mt < 4; mt++) {
      const int row0 = bm * 128 + wm * 64 + mt * 16 + quad * 4;
#pragma unroll
      for (int r = 0; r < 4; r++) {
        float v = acc[mt][nt][r] + bv;
        if (ACT == 1) {
          const float t = v * (0.7978845608f + 0.0356774081f * v * v);
          v = 0.5f * v * (1.0f + tanhf(t));
        }
        if (MODE == 0)
          ((u16*)Cv)[(size_t)(row0 + r) * N + col] = f2us(v);
        else
          atomicAdd((float*)Cv + (size_t)(row0 + r) * N + col, v);
      }
    }
  }
}

// ---------------------------------------------------------------------------
// RoPE in-place on bf16 qkv (q and k sections, first 32 dims of each head).
// ---------------------------------------------------------------------------
__global__ void rope_kernel(u16* __restrict__ qkv, const int* __restrict__ pos) {
  const int idx = blockIdx.x * 256 + threadIdx.x;  // 2048*32*2*16 total
  const int i = idx & 15;
  const int which = (idx >> 4) & 1;
  const int hh = (idx >> 5) & 31;
  const int s = idx >> 10;
  const float p = (float)pos[s];
  const float freq = p * expf(-0.57564627324851f * (float)i);  // ln(1e4)/16
  float sn, c;
  sincosf(freq, &sn, &c);
  u16* base = qkv + (size_t)s * (3 * DMODEL) + which * DMODEL + hh * HDIM + i;
  const float t0 = us2f(base[0]), t1 = us2f(base[16]);
  base[0] = f2us(t0 * c - t1 * sn);
  base[16] = f2us(t1 * c + t0 * sn);
}

// ---------------------------------------------------------------------------
// Flash attention (causal), bf16 in/out. Grid: (S/64, H). 4 waves; each wave
// owns 16 q-rows. KT=32 key columns per iteration; hd 80 padded to 96.
// ---------------------------------------------------------------------------
__global__ void attn_kernel(const u16* __restrict__ qkv, u16* __restrict__ y) {
  const int qt = (int)gridDim.x - 1 - (int)blockIdx.x;  // longest blocks first
  const int h = blockIdx.y;
  const int tid = threadIdx.x, wave = tid >> 6, lane = tid & 63;
  const int quad = lane >> 4, l15 = lane & 15;
  const int qbase = qt * 64;

  __shared__ __align__(16) u16 Qs[64 * 96];
  __shared__ __align__(16) u16 Ks[32 * 96];
  __shared__ __align__(16) u16 Vts[80 * 40];  // transposed V, stride 40
  __shared__ __align__(16) u16 Ps[4][16 * 40];

  for (int i = tid; i < 64 * 96; i += 256) Qs[i] = 0;
  for (int i = tid; i < 32 * 96; i += 256) Ks[i] = 0;
  __syncthreads();

  {  // stage Q once, folding in 1/sqrt(80)
    const int r = tid >> 2, c = tid & 3;
    const u16* src = qkv + (size_t)(qbase + r) * (3 * DMODEL) + h * HDIM + c * 20;
    u16* dst = Qs + r * 96 + c * 20;
#pragma unroll
    for (int j = 0; j < 5; j++) {
      ushort4 uv = *(const ushort4*)(src + j * 4);
      ushort4 ov;
      ov.x = f2us(us2f(uv.x) * 0.11180339887f);
      ov.y = f2us(us2f(uv.y) * 0.11180339887f);
      ov.z = f2us(us2f(uv.z) * 0.11180339887f);
      ov.w = f2us(us2f(uv.w) * 0.11180339887f);
      *(ushort4*)(dst + j * 4) = ov;
    }
  }

  float m_i[4], l_i[4];
  f32x4 oacc[5] = {};
#pragma unroll
  for (int r = 0; r < 4; r++) { m_i[r] = -1e30f; l_i[r] = 0.f; }

  const int n_iter = qt * 2 + 2;
  __syncthreads();

  for (int it = 0; it < n_iter; ++it) {
    const int kc0 = it * 32;
    if (tid < 128) {  // waves 0-1: stage K rows
      const int r = tid >> 2, c = tid & 3;
      const u16* src =
          qkv + (size_t)(kc0 + r) * (3 * DMODEL) + DMODEL + h * HDIM + c * 20;
      u16* dst = Ks + r * 96 + c * 20;
#pragma unroll
      for (int j = 0; j < 5; j++)
        *(ushort4*)(dst + j * 4) = *(const ushort4*)(src + j * 4);
    } else {  // waves 2-3: stage V transposed
      const int u = tid - 128;
      const int r = u >> 2, c = u & 3;
      const u16* src =
          qkv + (size_t)(kc0 + r) * (3 * DMODEL) + 2 * DMODEL + h * HDIM + c * 20;
#pragma unroll
      for (int j = 0; j < 5; j++) {
        ushort4 vv = *(const ushort4*)(src + j * 4);
        const int d0 = c * 20 + j * 4;
        Vts[(d0 + 0) * 40 + r] = vv.x;
        Vts[(d0 + 1) * 40 + r] = vv.y;
        Vts[(d0 + 2) * 40 + r] = vv.z;
        Vts[(d0 + 3) * 40 + r] = vv.w;
      }
    }
    __syncthreads();

    // S = Q K^T (16 rows x 32 cols per wave), 3 K-steps over padded hd=96
    f32x4 st[2] = {};
#pragma unroll
    for (int ks = 0; ks < 3; ks++) {
      bf16x8 aq = *(const bf16x8*)&Qs[(wave * 16 + l15) * 96 + ks * 32 + quad * 8];
#pragma unroll
      for (int t = 0; t < 2; t++) {
        bf16x8 bk = *(const bf16x8*)&Ks[(t * 16 + l15) * 96 + ks * 32 + quad * 8];
        st[t] = __builtin_amdgcn_mfma_f32_16x16x32_bf16(aq, bk, st[t], 0, 0, 0);
      }
    }

    // causal mask + online softmax (rows = quad*4+r, cols = t*16+l15)
    float sv[2][4], mx[4];
#pragma unroll
    for (int r = 0; r < 4; r++) {
      const int qr = qbase + wave * 16 + quad * 4 + r;
#pragma unroll
      for (int t = 0; t < 2; t++) {
        const int kc = kc0 + t * 16 + l15;
        sv[t][r] = (kc <= qr) ? st[t][r] : -1e30f;
      }
      mx[r] = fmaxf(sv[0][r], sv[1][r]);
    }
#pragma unroll
    for (int o = 1; o < 16; o <<= 1)
#pragma unroll
      for (int r = 0; r < 4; r++) mx[r] = fmaxf(mx[r], __shfl_xor(mx[r], o, 64));

    float alpha[4], rs[4];
#pragma unroll
    for (int r = 0; r < 4; r++) {
      const float mnew = fmaxf(m_i[r], mx[r]);
      alpha[r] = __expf(m_i[r] - mnew);
      m_i[r] = mnew;
      const float p0 = __expf(sv[0][r] - mnew);
      const float p1 = __expf(sv[1][r] - mnew);
      rs[r] = p0 + p1;
      Ps[wave][(quad * 4 + r) * 40 + l15] = f2us(p0);
      Ps[wave][(quad * 4 + r) * 40 + 16 + l15] = f2us(p1);
    }
#pragma unroll
    for (int o = 1; o < 16; o <<= 1)
#pragma unroll
      for (int r = 0; r < 4; r++) rs[r] += __shfl_xor(rs[r], o, 64);
#pragma unroll
    for (int r = 0; r < 4; r++) l_i[r] = l_i[r] * alpha[r] + rs[r];
#pragma unroll
    for (int dt = 0; dt < 5; dt++)
#pragma unroll
      for (int r = 0; r < 4; r++) oacc[dt][r] *= alpha[r];

    // O += P V  (P via LDS round-trip into A-layout; V from transposed LDS)
    bf16x8 pf = *(const bf16x8*)&Ps[wave][l15 * 40 + quad * 8];
#pragma unroll
    for (int dt = 0; dt < 5; dt++) {
      bf16x8 vf = *(const bf16x8*)&Vts[(dt * 16 + l15) * 40 + quad * 8];
      oacc[dt] = __builtin_amdgcn_mfma_f32_16x16x32_bf16(pf, vf, oacc[dt], 0, 0, 0);
    }
    __syncthreads();
  }

#pragma unroll
  for (int dt = 0; dt < 5; dt++)
#pragma unroll
    for (int r = 0; r < 4; r++) {
      const int row = qbase + wave * 16 + quad * 4 + r;
      y[(size_t)row * DMODEL + h * HDIM + dt * 16 + l15] = f2us(oacc[dt][r] / l_i[r]);
    }
}

extern "C" void kernel_launch(void* const* d_in, const int* in_sizes, int n_in,
                              void* d_out, int out_size, void* d_ws, size_t ws_size,
                              hipStream_t stream) {
  const float* x = (const float*)d_in[0];
  const int* pos = (const int*)d_in[1];
  // d_in[2] = mask (tril) -- causal structure applied analytically
  const float* ln_w = (const float*)d_in[3];
  const float* ln_b = (const float*)d_in[4];
  const float* wqkv_w = (const float*)d_in[5];
  const float* wqkv_b = (const float*)d_in[6];
  const float* wo_w = (const float*)d_in[7];
  const float* wo_b = (const float*)d_in[8];
  const float* w1_w = (const float*)d_in[9];
  const float* w1_b = (const float*)d_in[10];
  const float* w2_w = (const float*)d_in[11];
  const float* w2_b = (const float*)d_in[12];
  float* out = (float*)d_out;

  char* ws = (char*)d_ws;
  // layout (100 MB):
  //   [0,        52428800)  wbuf (bf16 weights, reused 4x)
  //   [52428800, 62914560)  h bf16
  //   [62914560, 104857600) C: ffn1 bf16 (42MB) -> later qkv (31.5) + yAtt (10.5)
  u16* wbuf = (u16*)(ws);
  u16* h = (u16*)(ws + 52428800);
  u16* ffn1 = (u16*)(ws + 62914560);
  u16* qkv = (u16*)(ws + 62914560);
  u16* yAtt = (u16*)(ws + 94371840);

  ln_kernel<<<S_LEN, 256, 0, stream>>>(x, ln_w, ln_b, h);
  initout_kernel<<<(S_LEN * DMODEL / 4) / 256, 256, 0, stream>>>(x, wo_b, w2_b, out);

  // FFN branch (ffn1 dies before qkv overlays it)
  f2b_kernel<<<(DINTER * DMODEL) / 2048, 256, 0, stream>>>(w1_w, wbuf);
  gemm_bt<1, 0><<<dim3(DINTER / 128, S_LEN / 128, 1), 256, 0, stream>>>(
      h, wbuf, w1_b, ffn1, S_LEN, DINTER, DMODEL);
  f2b_kernel<<<(DMODEL * DINTER) / 2048, 256, 0, stream>>>(w2_w, wbuf);
  gemm_bt<0, 2><<<dim3(DMODEL / 128, S_LEN / 128, 4), 256, 0, stream>>>(
      ffn1, wbuf, w2_b, out, S_LEN, DMODEL, DINTER);

  // Attention branch
  f2b_kernel<<<(3 * DMODEL * DMODEL) / 2048, 256, 0, stream>>>(wqkv_w, wbuf);
  gemm_bt<0, 0><<<dim3(3 * DMODEL / 128, S_LEN / 128, 1), 256, 0, stream>>>(
      h, wbuf, wqkv_b, qkv, S_LEN, 3 * DMODEL, DMODEL);
  rope_kernel<<<(S_LEN * NHEADS * 2 * 16) / 256, 256, 0, stream>>>(qkv, pos);
  attn_kernel<<<dim3(S_LEN / 64, NHEADS), 256, 0, stream>>>(qkv, yAtt);
  f2b_kernel<<<(DMODEL * DMODEL) / 2048, 256, 0, stream>>>(wo_w, wbuf);
  gemm_bt<0, 2><<<dim3(DMODEL / 128, S_LEN / 128, 2), 256, 0, stream>>>(
      yAtt, wbuf, wo_b, out, S_LEN, DMODEL, DMODEL);
}

// Round 4
// 1003.831 us; speedup vs baseline: 1.0712x; 1.0266x over previous
//
#include <hip/hip_runtime.h>
#include <cstdint>

#define S_LEN 2048
#define DMODEL 2560
#define NHEADS 32
#define HDIM 80
#define DINTER 10240

typedef unsigned short u16;
typedef __bf16 bf16x8 __attribute__((ext_vector_type(8)));
typedef float f32x4 __attribute__((ext_vector_type(4)));

__device__ __forceinline__ float us2f(u16 u) {
  return __builtin_bit_cast(float, ((uint32_t)u) << 16);
}
__device__ __forceinline__ u16 f2us(float f) {
  uint32_t x = __builtin_bit_cast(uint32_t, f);
  x += 0x7fffu + ((x >> 16) & 1u);
  return (u16)(x >> 16);
}

typedef __attribute__((address_space(1))) void gas_void;
typedef __attribute__((address_space(3))) void las_void;
__device__ __forceinline__ void gld16(const void* g, void* l) {
  __builtin_amdgcn_global_load_lds((gas_void*)g, (las_void*)l, 16, 0, 0);
}

// ---------------------------------------------------------------------------
// fp32 -> bf16 conversion, 8 elements/thread
// ---------------------------------------------------------------------------
__global__ void f2b_kernel(const float* __restrict__ src, u16* __restrict__ dst) {
  const size_t i = ((size_t)blockIdx.x * 256 + threadIdx.x) * 8;
  const float4 a = *(const float4*)(src + i);
  const float4 b = *(const float4*)(src + i + 4);
  u16 o[8] = {f2us(a.x), f2us(a.y), f2us(a.z), f2us(a.w),
              f2us(b.x), f2us(b.y), f2us(b.z), f2us(b.w)};
  *(uint4*)(dst + i) = *(uint4*)o;
}

// ---------------------------------------------------------------------------
// out = x + wo_b[col] + w2_b[col]  (fp32)
// ---------------------------------------------------------------------------
__global__ void initout_kernel(const float* __restrict__ x,
                               const float* __restrict__ wo_b,
                               const float* __restrict__ w2_b,
                               float* __restrict__ out) {
  const size_t idx = ((size_t)blockIdx.x * 256 + threadIdx.x) * 4;
  const int c0 = (int)(idx % DMODEL);
  const float4 vx = *(const float4*)(x + idx);
  const float4 b1 = *(const float4*)(wo_b + c0);
  const float4 b2 = *(const float4*)(w2_b + c0);
  float4 vo;
  vo.x = vx.x + b1.x + b2.x;
  vo.y = vx.y + b1.y + b2.y;
  vo.z = vx.z + b1.z + b2.z;
  vo.w = vx.w + b1.w + b2.w;
  *(float4*)(out + idx) = vo;
}

// ---------------------------------------------------------------------------
// LayerNorm: fp32 in, bf16 out. One block per row (2560 = 256 x 10)
// ---------------------------------------------------------------------------
__global__ void ln_kernel(const float* __restrict__ x, const float* __restrict__ w,
                          const float* __restrict__ b, u16* __restrict__ h) {
  const int s = blockIdx.x, tid = threadIdx.x;
  const float* xr = x + (size_t)s * DMODEL;
  float v[10];
  float sum = 0.f, sq = 0.f;
#pragma unroll
  for (int j = 0; j < 10; j++) {
    v[j] = xr[tid + j * 256];
    sum += v[j];
    sq += v[j] * v[j];
  }
#pragma unroll
  for (int o = 32; o > 0; o >>= 1) {
    sum += __shfl_down(sum, o, 64);
    sq += __shfl_down(sq, o, 64);
  }
  __shared__ float red[8];
  const int wave = tid >> 6, lane = tid & 63;
  if (lane == 0) { red[wave] = sum; red[4 + wave] = sq; }
  __syncthreads();
  sum = red[0] + red[1] + red[2] + red[3];
  sq = red[4] + red[5] + red[6] + red[7];
  const float mu = sum * (1.0f / DMODEL);
  const float var = sq * (1.0f / DMODEL) - mu * mu;
  const float rstd = rsqrtf(var + 1e-5f);
  u16* hr = h + (size_t)s * DMODEL;
#pragma unroll
  for (int j = 0; j < 10; j++) {
    const int d = tid + j * 256;
    hr[d] = f2us((v[j] - mu) * rstd * w[d] + b[d]);
  }
}

// ---------------------------------------------------------------------------
// GEMM: C[M][N] = act(A[M][K] * B[N][K]^T [+ bias[N]]); bf16 in, fp32 acc.
// 128x128 tile, BK=32, 256 threads. XOR chunk swizzle in LDS: 16B chunk c of
// row r stored at position c ^ ((r>>2)&3) -> fragment ds_read_b128 hits all
// 8 bank groups (was 8-way conflict). Staging coalescing unchanged (perm
// within a 64B row segment).
// grid.z = K-split; MODE: 0 bf16 store (+bias), 2 fp32 atomicAdd.
// ---------------------------------------------------------------------------
template <int ACT, int MODE>
__global__ void gemm_bt(const u16* __restrict__ A, const u16* __restrict__ B,
                        const float* __restrict__ bias, void* __restrict__ Cv,
                        int M, int N, int K) {
  __shared__ __align__(16) u16 As[128 * 32];
  __shared__ __align__(16) u16 Bs[128 * 32];
  const int tid = threadIdx.x;
  const int wave = tid >> 6, lane = tid & 63;
  const int quad = lane >> 4, l15 = lane & 15;
  const int wm = wave >> 1, wn = wave & 1;

  const int flat = blockIdx.x + gridDim.x * blockIdx.y;
  const int r_ = flat & 63;
  const int bn = (flat >> 6) * 4 + (r_ & 3);
  const int bm = r_ >> 2;

  const int Kc = K / gridDim.z;
  const int kbeg = blockIdx.z * Kc;

  const int srow = lane >> 2;
  const int scol = (((lane & 3) ^ ((lane >> 4) & 3)) * 8);  // XOR swizzle
  const size_t aBase = (size_t)(bm * 128 + wave * 32 + srow) * K + scol;
  const size_t aBase2 = aBase + (size_t)16 * K;
  const size_t bBase = (size_t)(bn * 128 + wave * 32 + srow) * K + scol;
  const size_t bBase2 = bBase + (size_t)16 * K;
  u16* AsW0 = As + (wave * 32) * 32;
  u16* AsW1 = As + (wave * 32 + 16) * 32;
  u16* BsW0 = Bs + (wave * 32) * 32;
  u16* BsW1 = Bs + (wave * 32 + 16) * 32;

  const int fcol = (quad ^ ((l15 >> 2) & 3)) * 8;  // swizzled read position

  f32x4 acc[4][4] = {};

  for (int k0 = kbeg; k0 < kbeg + Kc; k0 += 32) {
    gld16(A + aBase + k0, AsW0);
    gld16(A + aBase2 + k0, AsW1);
    gld16(B + bBase + k0, BsW0);
    gld16(B + bBase2 + k0, BsW1);
    __syncthreads();
    bf16x8 af[4], bf[4];
#pragma unroll
    for (int mt = 0; mt < 4; mt++)
      af[mt] = *(const bf16x8*)&As[(wm * 64 + mt * 16 + l15) * 32 + fcol];
#pragma unroll
    for (int nt = 0; nt < 4; nt++)
      bf[nt] = *(const bf16x8*)&Bs[(wn * 64 + nt * 16 + l15) * 32 + fcol];
#pragma unroll
    for (int mt = 0; mt < 4; mt++)
#pragma unroll
      for (int nt = 0; nt < 4; nt++)
        acc[mt][nt] =
            __builtin_amdgcn_mfma_f32_16x16x32_bf16(af[mt], bf[nt], acc[mt][nt], 0, 0, 0);
    __syncthreads();
  }

#pragma unroll
  for (int nt = 0; nt < 4; nt++) {
    const int col = bn * 128 + wn * 64 + nt * 16 + l15;
    const float bv = (MODE == 0) ? bias[col] : 0.f;
#pragma unroll
    for (int mt = 0; mt < 4; mt++) {
      const int row0 = bm * 128 + wm * 64 + mt * 16 + quad * 4;
#pragma unroll
      for (int r = 0; r < 4; r++) {
        float v = acc[mt][nt][r] + bv;
        if (ACT == 1) {
          const float t = v * (0.7978845608f + 0.0356774081f * v * v);
          v = 0.5f * v * (1.0f + tanhf(t));
        }
        if (MODE == 0)
          ((u16*)Cv)[(size_t)(row0 + r) * N + col] = f2us(v);
        else
          atomicAdd((float*)Cv + (size_t)(row0 + r) * N + col, v);
      }
    }
  }
}

// ---------------------------------------------------------------------------
// RoPE in-place on bf16 qkv (q and k sections, first 32 dims of each head).
// ---------------------------------------------------------------------------
__global__ void rope_kernel(u16* __restrict__ qkv, const int* __restrict__ pos) {
  const int idx = blockIdx.x * 256 + threadIdx.x;
  const int i = idx & 15;
  const int which = (idx >> 4) & 1;
  const int hh = (idx >> 5) & 31;
  const int s = idx >> 10;
  const float p = (float)pos[s];
  const float freq = p * expf(-0.57564627324851f * (float)i);
  float sn, c;
  sincosf(freq, &sn, &c);
  u16* base = qkv + (size_t)s * (3 * DMODEL) + which * DMODEL + hh * HDIM + i;
  const float t0 = us2f(base[0]), t1 = us2f(base[16]);
  base[0] = f2us(t0 * c - t1 * sn);
  base[16] = f2us(t1 * c + t0 * sn);
}

// ---------------------------------------------------------------------------
// Flash attention (causal), bf16. Grid (S/64, H), 256 thr = 4 waves; each
// wave owns 16 q-rows. KT=64 keys/iter (halves barriers + P-roundtrips vs
// KT=32). hd 80 padded to 96 for 3 K=32 MFMA steps. Conflict-free strides:
// Qs/Ks 104, Vts 88, Ps two 16x40 tiles.
// ---------------------------------------------------------------------------
__global__ void attn_kernel(const u16* __restrict__ qkv, u16* __restrict__ y) {
  const int qt = (int)gridDim.x - 1 - (int)blockIdx.x;  // longest first
  const int h = blockIdx.y;
  const int tid = threadIdx.x, wave = tid >> 6, lane = tid & 63;
  const int quad = lane >> 4, l15 = lane & 15;
  const int qbase = qt * 64;

  __shared__ __align__(16) u16 Qs[64 * 104];
  __shared__ __align__(16) u16 Ks[64 * 104];
  __shared__ __align__(16) u16 Vts[80 * 88];   // [dim][key], stride 88
  __shared__ __align__(16) u16 Ps[4][2][16 * 40];

  for (int i = tid; i < 64 * 104; i += 256) { Qs[i] = 0; Ks[i] = 0; }
  __syncthreads();

  {  // stage Q once, folding in 1/sqrt(80)
    const int r = tid >> 2, c = tid & 3;
    const u16* src = qkv + (size_t)(qbase + r) * (3 * DMODEL) + h * HDIM + c * 20;
    u16* dst = Qs + r * 104 + c * 20;
#pragma unroll
    for (int j = 0; j < 5; j++) {
      ushort4 uv = *(const ushort4*)(src + j * 4);
      ushort4 ov;
      ov.x = f2us(us2f(uv.x) * 0.11180339887f);
      ov.y = f2us(us2f(uv.y) * 0.11180339887f);
      ov.z = f2us(us2f(uv.z) * 0.11180339887f);
      ov.w = f2us(us2f(uv.w) * 0.11180339887f);
      *(ushort4*)(dst + j * 4) = ov;
    }
  }

  float m_i[4], l_i[4];
  f32x4 oacc[5] = {};
#pragma unroll
  for (int r = 0; r < 4; r++) { m_i[r] = -1e30f; l_i[r] = 0.f; }

  const int n_iter = qt + 1;
  __syncthreads();

  for (int it = 0; it < n_iter; ++it) {
    const int kc0 = it * 64;
    if (tid < 128) {  // waves 0-1: stage 64 K rows (2 threads/row)
      const int r = tid >> 1, c = (tid & 1) * 40;
      const u16* src =
          qkv + (size_t)(kc0 + r) * (3 * DMODEL) + DMODEL + h * HDIM + c;
      u16* dst = Ks + r * 104 + c;
#pragma unroll
      for (int j = 0; j < 10; j++)
        *(ushort4*)(dst + j * 4) = *(const ushort4*)(src + j * 4);
    } else {  // waves 2-3: stage 64 V rows transposed
      const int u = tid - 128;
      const int r = u >> 1, c0 = (u & 1) * 40;
      const u16* src =
          qkv + (size_t)(kc0 + r) * (3 * DMODEL) + 2 * DMODEL + h * HDIM + c0;
#pragma unroll
      for (int j = 0; j < 10; j++) {
        ushort4 vv = *(const ushort4*)(src + j * 4);
        const int d0 = c0 + j * 4;
        Vts[(d0 + 0) * 88 + r] = vv.x;
        Vts[(d0 + 1) * 88 + r] = vv.y;
        Vts[(d0 + 2) * 88 + r] = vv.z;
        Vts[(d0 + 3) * 88 + r] = vv.w;
      }
    }
    __syncthreads();

    // S = Q K^T : 16 rows x 64 cols per wave, 3 K-steps over padded hd=96
    f32x4 st[4] = {};
    bf16x8 aq[3];
#pragma unroll
    for (int ks = 0; ks < 3; ks++)
      aq[ks] = *(const bf16x8*)&Qs[(wave * 16 + l15) * 104 + ks * 32 + quad * 8];
#pragma unroll
    for (int ks = 0; ks < 3; ks++)
#pragma unroll
      for (int t = 0; t < 4; t++) {
        bf16x8 bk = *(const bf16x8*)&Ks[(t * 16 + l15) * 104 + ks * 32 + quad * 8];
        st[t] = __builtin_amdgcn_mfma_f32_16x16x32_bf16(aq[ks], bk, st[t], 0, 0, 0);
      }

    // causal mask + online softmax (rows = quad*4+r, cols = t*16+l15)
    float sv[4][4], mx[4];
#pragma unroll
    for (int r = 0; r < 4; r++) {
      const int qr = qbase + wave * 16 + quad * 4 + r;
#pragma unroll
      for (int t = 0; t < 4; t++) {
        const int kc = kc0 + t * 16 + l15;
        sv[t][r] = (kc <= qr) ? st[t][r] : -1e30f;
      }
      mx[r] = fmaxf(fmaxf(sv[0][r], sv[1][r]), fmaxf(sv[2][r], sv[3][r]));
    }
#pragma unroll
    for (int o = 1; o < 16; o <<= 1)
#pragma unroll
      for (int r = 0; r < 4; r++) mx[r] = fmaxf(mx[r], __shfl_xor(mx[r], o, 64));

    float alpha[4], rs[4];
#pragma unroll
    for (int r = 0; r < 4; r++) {
      const float mnew = fmaxf(m_i[r], mx[r]);
      alpha[r] = __expf(m_i[r] - mnew);
      m_i[r] = mnew;
      const float p0 = __expf(sv[0][r] - mnew);
      const float p1 = __expf(sv[1][r] - mnew);
      const float p2 = __expf(sv[2][r] - mnew);
      const float p3 = __expf(sv[3][r] - mnew);
      rs[r] = (p0 + p1) + (p2 + p3);
      const int ro = (quad * 4 + r) * 40;
      Ps[wave][0][ro + l15] = f2us(p0);
      Ps[wave][0][ro + 16 + l15] = f2us(p1);
      Ps[wave][1][ro + l15] = f2us(p2);
      Ps[wave][1][ro + 16 + l15] = f2us(p3);
    }
#pragma unroll
    for (int o = 1; o < 16; o <<= 1)
#pragma unroll
      for (int r = 0; r < 4; r++) rs[r] += __shfl_xor(rs[r], o, 64);
#pragma unroll
    for (int r = 0; r < 4; r++) l_i[r] = l_i[r] * alpha[r] + rs[r];
#pragma unroll
    for (int dt = 0; dt < 5; dt++)
#pragma unroll
      for (int r = 0; r < 4; r++) oacc[dt][r] *= alpha[r];

    // O += P V  (P via per-wave LDS round-trip into A-layout)
    bf16x8 pf0 = *(const bf16x8*)&Ps[wave][0][l15 * 40 + quad * 8];
    bf16x8 pf1 = *(const bf16x8*)&Ps[wave][1][l15 * 40 + quad * 8];
#pragma unroll
    for (int dt = 0; dt < 5; dt++) {
      bf16x8 vf0 = *(const bf16x8*)&Vts[(dt * 16 + l15) * 88 + quad * 8];
      bf16x8 vf1 = *(const bf16x8*)&Vts[(dt * 16 + l15) * 88 + 32 + quad * 8];
      oacc[dt] = __builtin_amdgcn_mfma_f32_16x16x32_bf16(pf0, vf0, oacc[dt], 0, 0, 0);
      oacc[dt] = __builtin_amdgcn_mfma_f32_16x16x32_bf16(pf1, vf1, oacc[dt], 0, 0, 0);
    }
    __syncthreads();
  }

#pragma unroll
  for (int dt = 0; dt < 5; dt++)
#pragma unroll
    for (int r = 0; r < 4; r++) {
      const int row = qbase + wave * 16 + quad * 4 + r;
      y[(size_t)row * DMODEL + h * HDIM + dt * 16 + l15] = f2us(oacc[dt][r] / l_i[r]);
    }
}

extern "C" void kernel_launch(void* const* d_in, const int* in_sizes, int n_in,
                              void* d_out, int out_size, void* d_ws, size_t ws_size,
                              hipStream_t stream) {
  const float* x = (const float*)d_in[0];
  const int* pos = (const int*)d_in[1];
  const float* ln_w = (const float*)d_in[3];
  const float* ln_b = (const float*)d_in[4];
  const float* wqkv_w = (const float*)d_in[5];
  const float* wqkv_b = (const float*)d_in[6];
  const float* wo_w = (const float*)d_in[7];
  const float* wo_b = (const float*)d_in[8];
  const float* w1_w = (const float*)d_in[9];
  const float* w1_b = (const float*)d_in[10];
  const float* w2_w = (const float*)d_in[11];
  const float* w2_b = (const float*)d_in[12];
  float* out = (float*)d_out;

  char* ws = (char*)d_ws;
  // layout (100 MB):
  //   [0,        52428800)  wbuf (bf16 weights, reused 4x)
  //   [52428800, 62914560)  h bf16
  //   [62914560, 104857600) ffn1 bf16 (42MB) -> later qkv (31.5) + yAtt (10.5)
  u16* wbuf = (u16*)(ws);
  u16* h = (u16*)(ws + 52428800);
  u16* ffn1 = (u16*)(ws + 62914560);
  u16* qkv = (u16*)(ws + 62914560);
  u16* yAtt = (u16*)(ws + 94371840);

  ln_kernel<<<S_LEN, 256, 0, stream>>>(x, ln_w, ln_b, h);
  initout_kernel<<<(S_LEN * DMODEL / 4) / 256, 256, 0, stream>>>(x, wo_b, w2_b, out);

  // FFN branch (ffn1 dies before qkv overlays it)
  f2b_kernel<<<(DINTER * DMODEL) / 2048, 256, 0, stream>>>(w1_w, wbuf);
  gemm_bt<1, 0><<<dim3(DINTER / 128, S_LEN / 128, 1), 256, 0, stream>>>(
      h, wbuf, w1_b, ffn1, S_LEN, DINTER, DMODEL);
  f2b_kernel<<<(DMODEL * DINTER) / 2048, 256, 0, stream>>>(w2_w, wbuf);
  gemm_bt<0, 2><<<dim3(DMODEL / 128, S_LEN / 128, 4), 256, 0, stream>>>(
      ffn1, wbuf, w2_b, out, S_LEN, DMODEL, DINTER);

  // Attention branch
  f2b_kernel<<<(3 * DMODEL * DMODEL) / 2048, 256, 0, stream>>>(wqkv_w, wbuf);
  gemm_bt<0, 0><<<dim3(3 * DMODEL / 128, S_LEN / 128, 1), 256, 0, stream>>>(
      h, wbuf, wqkv_b, qkv, S_LEN, 3 * DMODEL, DMODEL);
  rope_kernel<<<(S_LEN * NHEADS * 2 * 16) / 256, 256, 0, stream>>>(qkv, pos);
  attn_kernel<<<dim3(S_LEN / 64, NHEADS), 256, 0, stream>>>(qkv, yAtt);
  f2b_kernel<<<(DMODEL * DMODEL) / 2048, 256, 0, stream>>>(wo_w, wbuf);
  gemm_bt<0, 2><<<dim3(DMODEL / 128, S_LEN / 128, 2), 256, 0, stream>>>(
      yAtt, wbuf, wo_b, out, S_LEN, DMODEL, DMODEL);
}